// Round 6
// baseline (211.884 us; speedup 1.0000x reference)
//
#include <hip/hip_runtime.h>

// KMeans soft-assignment via bf16 hi/lo split MFMA (3 passes), fused softmax.
// logits = (2*x.c - ||c||^2)/T, T=0.1; ||x||^2 cancels in softmax.
// R6: register-direct GEMM (no LDS/barriers in K-loop) + deep software
// pipeline: 2-wave/SIMD VGPR budget, double-buffered half-chunk B fragments
// (16 loads in flight), A prefetch one chunk ahead.
// x: [32768,256] f32, c: [512,256] f32, out: [32768,512] f32
#define NROWS 32768
#define KC 512
#define DDIM 256
#define BM 64
#define BK 32
#define KCH (DDIM / BK)   // 8 k-chunks

typedef __attribute__((ext_vector_type(8))) short bf16x8;
typedef __attribute__((ext_vector_type(4))) float f32x4;

union U8 { unsigned short u[8]; bf16x8 v; };

__device__ __forceinline__ unsigned short f2bf(float f) {   // RNE f32->bf16
    union { float f; unsigned int u; } a; a.f = f;
    unsigned int r = a.u + 0x7fffu + ((a.u >> 16) & 1u);
    return (unsigned short)(r >> 16);
}
__device__ __forceinline__ float bf2f(unsigned short h) {
    union { unsigned int u; float f; } a; a.u = ((unsigned int)h) << 16;
    return a.f;
}

// ---- prep: c f32 -> row-major bf16 hi/lo tables + csq10 = 10*||c||^2 ----
__global__ __launch_bounds__(64) void prep_c(const float* __restrict__ c,
                                             unsigned short* __restrict__ bhi,
                                             unsigned short* __restrict__ blo,
                                             float* __restrict__ csq10) {
    const int n = blockIdx.x, lane = threadIdx.x;
    float4 v = ((const float4*)(c + (size_t)n * DDIM))[lane];
    float vv[4] = {v.x, v.y, v.z, v.w};
    unsigned short hh[4], ll[4];
    float ssq = 0.f;
    #pragma unroll
    for (int i = 0; i < 4; ++i) {
        ssq += vv[i] * vv[i];
        hh[i] = f2bf(vv[i]);
        ll[i] = f2bf(vv[i] - bf2f(hh[i]));
    }
    #pragma unroll
    for (int off = 32; off; off >>= 1) ssq += __shfl_xor(ssq, off);
    if (lane == 0) csq10[n] = 10.f * ssq;
    *(ushort4*)(bhi + (size_t)n * DDIM + lane * 4) = make_ushort4(hh[0], hh[1], hh[2], hh[3]);
    *(ushort4*)(blo + (size_t)n * DDIM + lane * 4) = make_ushort4(ll[0], ll[1], ll[2], ll[3]);
}

// ---- main: 512 blocks x 512 threads (8 waves = 4 M-groups x 2 N-groups) ----
__global__ __launch_bounds__(512, 2) void kmeans_mfma(
    const float* __restrict__ x, const unsigned short* __restrict__ bhi,
    const unsigned short* __restrict__ blo, const float* __restrict__ csq10,
    float* __restrict__ out) {
    __shared__ float lbuf[32 * 516];   // 66 KB transpose buffer (pad 516: 2-way, free)
    __shared__ float red[2][2][BM];
    __shared__ float invS[BM];

    const int tid  = threadIdx.x;
    const int w    = tid >> 6, lane = tid & 63;
    const int wm   = w >> 1, wn = w & 1;
    const int cc   = lane & 15, q = lane >> 4;
    const int row0 = blockIdx.x * BM;

    f32x4 acc[16];
    #pragma unroll
    for (int t = 0; t < 16; ++t) acc[t] = (f32x4){0.f, 0.f, 0.f, 0.f};

    // A: this lane owns x row (row0 + wm*16 + cc), k-octet q*8 within each chunk
    const float* xrow = x + (size_t)(row0 + wm * 16 + cc) * DDIM + q * 8;
    // B: this lane owns cluster col base (wn*256 + cc), k-octet q*8; t stride 16 rows
    const unsigned short* bh0 = bhi + (size_t)(wn * 256 + cc) * DDIM + q * 8;
    const unsigned short* bl0 = blo + (size_t)(wn * 256 + cc) * DDIM + q * 8;
    const int bbase = wn * 256 + cc;

    // ---- pipelined K-loop ----
    bf16x8 B0h[8], B0l[8], B1h[8], B1l[8];
    // preload half0 of ks=0
    #pragma unroll
    for (int t = 0; t < 8; ++t) {
        B0h[t] = *(const bf16x8*)(bh0 + (size_t)t * 16 * DDIM);
        B0l[t] = *(const bf16x8*)(bl0 + (size_t)t * 16 * DDIM);
    }
    float4 va = *(const float4*)xrow;
    float4 vb = *(const float4*)(xrow + 4);

    #pragma unroll
    for (int ks = 0; ks < KCH; ++ks) {
        const int k0 = ks * BK;
        const int kn = ((ks + 1) & (KCH - 1)) * BK;   // wrap: last-iter reloads are cache hits

        // convert A fragment for this chunk
        float vv[8] = {va.x, va.y, va.z, va.w, vb.x, vb.y, vb.z, vb.w};
        U8    Ah, Al;
        #pragma unroll
        for (int j = 0; j < 8; ++j) {
            Ah.u[j] = f2bf(vv[j]);
            Al.u[j] = f2bf(vv[j] - bf2f(Ah.u[j]));
        }
        const bf16x8 ah = Ah.v, al = Al.v;

        // prefetch A for next chunk
        float4 van = *(const float4*)(xrow + kn);
        float4 vbn = *(const float4*)(xrow + kn + 4);

        // issue loads for half1 of this chunk (t=8..15)
        #pragma unroll
        for (int t = 0; t < 8; ++t) {
            B1h[t] = *(const bf16x8*)(bh0 + k0 + (size_t)(8 + t) * 16 * DDIM);
            B1l[t] = *(const bf16x8*)(bl0 + k0 + (size_t)(8 + t) * 16 * DDIM);
        }
        // MFMA half0 (overlaps half1 loads)
        #pragma unroll
        for (int t = 0; t < 8; ++t) {
            acc[t] = __builtin_amdgcn_mfma_f32_16x16x32_bf16(ah, B0h[t], acc[t], 0, 0, 0);
            acc[t] = __builtin_amdgcn_mfma_f32_16x16x32_bf16(ah, B0l[t], acc[t], 0, 0, 0);
            acc[t] = __builtin_amdgcn_mfma_f32_16x16x32_bf16(al, B0h[t], acc[t], 0, 0, 0);
        }
        // issue loads for half0 of next chunk
        #pragma unroll
        for (int t = 0; t < 8; ++t) {
            B0h[t] = *(const bf16x8*)(bh0 + kn + (size_t)t * 16 * DDIM);
            B0l[t] = *(const bf16x8*)(bl0 + kn + (size_t)t * 16 * DDIM);
        }
        // MFMA half1 (overlaps next-chunk loads)
        #pragma unroll
        for (int t = 0; t < 8; ++t) {
            acc[8 + t] = __builtin_amdgcn_mfma_f32_16x16x32_bf16(ah, B1h[t], acc[8 + t], 0, 0, 0);
            acc[8 + t] = __builtin_amdgcn_mfma_f32_16x16x32_bf16(ah, B1l[t], acc[8 + t], 0, 0, 0);
            acc[8 + t] = __builtin_amdgcn_mfma_f32_16x16x32_bf16(al, B1h[t], acc[8 + t], 0, 0, 0);
        }
        va = van; vb = vbn;
    }

    // ---- softmax stats (C/D layout: col = cc, row = q*4+g within 16) ----
    float csqv[16];
    #pragma unroll
    for (int t = 0; t < 16; ++t) csqv[t] = csq10[bbase + t * 16];
    const int rbase = wm * 16 + q * 4;
    float     M[4];
    #pragma unroll
    for (int g = 0; g < 4; ++g) {
        float pm = -1e30f;
        #pragma unroll
        for (int t = 0; t < 16; ++t) pm = fmaxf(pm, 20.f * acc[t][g] - csqv[t]);
        #pragma unroll
        for (int off = 1; off < 16; off <<= 1) pm = fmaxf(pm, __shfl_xor(pm, off));
        if (cc == 0) red[0][wn][rbase + g] = pm;
        M[g] = pm;
    }
    __syncthreads();
    #pragma unroll
    for (int g = 0; g < 4; ++g) {
        M[g]     = fmaxf(M[g], red[0][1 - wn][rbase + g]);
        float ps = 0.f;
        #pragma unroll
        for (int t = 0; t < 16; ++t) ps += __expf(20.f * acc[t][g] - csqv[t] - M[g]);
        #pragma unroll
        for (int off = 1; off < 16; off <<= 1) ps += __shfl_xor(ps, off);
        if (cc == 0) red[1][wn][rbase + g] = ps;
    }
    __syncthreads();
    if (tid < BM) invS[tid] = 1.f / (red[1][0][tid] + red[1][1][tid]);
    __syncthreads();

    // ---- transpose epilogue: 2 passes of 32 rows through lbuf, dense stores ----
    #pragma unroll
    for (int p = 0; p < 2; ++p) {
        if ((wm >> 1) == p) {
            const int lr = (wm & 1) * 16 + q * 4;
            #pragma unroll
            for (int g = 0; g < 4; ++g) {
                float mg = M[g];
                #pragma unroll
                for (int t = 0; t < 16; ++t)
                    lbuf[(lr + g) * 516 + wn * 256 + t * 16 + cc] =
                        __expf(20.f * acc[t][g] - csqv[t] - mg);
            }
        }
        __syncthreads();
        #pragma unroll
        for (int j = 0; j < 8; ++j) {
            const int   f    = j * 512 + tid;     // 0..4095 float4 slots
            const int   lrow = f >> 7;            // 0..31
            const int   c4   = f & 127;
            float4      v    = *(const float4*)&lbuf[lrow * 516 + c4 * 4];
            const float inv  = invS[p * 32 + lrow];
            *(float4*)(out + (size_t)(row0 + p * 32 + lrow) * KC + c4 * 4) =
                make_float4(v.x * inv, v.y * inv, v.z * inv, v.w * inv);
        }
        __syncthreads();
    }
}

extern "C" void kernel_launch(void* const* d_in, const int* in_sizes, int n_in,
                              void* d_out, int out_size, void* d_ws, size_t ws_size,
                              hipStream_t stream) {
    const float* x   = (const float*)d_in[0];
    const float* c   = (const float*)d_in[1];
    float*       out = (float*)d_out;

    unsigned short* bhi   = (unsigned short*)d_ws;                 // 256 KB
    unsigned short* blo   = bhi + (size_t)KC * DDIM;               // 256 KB
    float*          csq10 = (float*)(blo + (size_t)KC * DDIM);     // 2 KB

    prep_c<<<KC, 64, 0, stream>>>(c, bhi, blo, csq10);
    kmeans_mfma<<<NROWS / BM, 512, 0, stream>>>(x, bhi, blo, csq10, out);
}